// Round 5
// baseline (727.408 us; speedup 1.0000x reference)
//
#include <hip/hip_runtime.h>
#include <stdint.h>

#define B_ 16
#define C_ 512
#define T_ 4096
#define H_ 8
#define D_ 64
#define SCALE_ 0.125f
#define EPS_ 1e-5f

using ushortT = unsigned short;
using ushort8 = __attribute__((ext_vector_type(8))) unsigned short;
using short8  = __attribute__((ext_vector_type(8))) short;
using floatx4 = __attribute__((ext_vector_type(4))) float;

__device__ __forceinline__ float bf2f(ushortT u) {
  union { unsigned int i; float f; } x; x.i = ((unsigned int)u) << 16; return x.f;
}
__device__ __forceinline__ ushortT f2bf(float f) {
  union { float f; unsigned int i; } x; x.f = f;
  unsigned int r = x.i + 0x7fffu + ((x.i >> 16) & 1u);
  return (ushortT)(r >> 16);
}

// async 16B global->LDS DMA; LDS dest = wave-uniform base + lane*16
#define GLD16(gp, lp)                                                          \
  __builtin_amdgcn_global_load_lds(                                            \
      (const __attribute__((address_space(1))) unsigned int*)(gp),             \
      (__attribute__((address_space(3))) unsigned int*)(lp), 16, 0, 0)

// ---------------- fp32 -> bf16 convert (weights) ----------------
__global__ __launch_bounds__(256) void cvt_f32_bf16(const float* __restrict__ src,
                                                    ushortT* __restrict__ dst, int n4) {
  int i = blockIdx.x * 256 + threadIdx.x;
  if (i >= n4) return;
  floatx4 v = *(const floatx4*)(src + (size_t)i * 4);
  unsigned int p0 = (unsigned int)f2bf(v[0]) | ((unsigned int)f2bf(v[1]) << 16);
  unsigned int p1 = (unsigned int)f2bf(v[2]) | ((unsigned int)f2bf(v[3]) << 16);
  *(unsigned long long*)(dst + (size_t)i * 4) =
      (unsigned long long)p0 | ((unsigned long long)p1 << 32);
}

// ---------------- zero init (ct2 + stats, contiguous) ----------------
__global__ void zero_f32(float* p, int n4) {
  int i = blockIdx.x * 256 + threadIdx.x;
  if (i < n4) ((floatx4*)p)[i] = (floatx4){0.f, 0.f, 0.f, 0.f};
}

// ---------------- transpose x[b][c][t] (fp32) -> xT[b][t][c] (bf16) ----------------
__global__ __launch_bounds__(256) void transpose_x(const float* __restrict__ x,
                                                   ushortT* __restrict__ xT) {
  __shared__ ushortT tile[64][65];
  int b = blockIdx.z;
  int t0 = blockIdx.x * 64, c0 = blockIdx.y * 64;
  const float* xb = x + (size_t)b * C_ * T_;
  ushortT* xTb = xT + (size_t)b * T_ * C_;
  for (int i = threadIdx.x; i < 4096; i += 256) {
    int cc = i >> 6, tt = i & 63;
    tile[cc][tt] = f2bf(xb[(size_t)(c0 + cc) * T_ + t0 + tt]);
  }
  __syncthreads();
  for (int i = threadIdx.x; i < 4096; i += 256) {
    int tt = i >> 6, cc = i & 63;
    xTb[(size_t)(t0 + tt) * C_ + c0 + cc] = tile[cc][tt];
  }
}

// ---------------- bf16 GEMM: C[m][n] = sum_k A[m][k]*Bt[n][k] ----------------
// grid: (N/128, M/128, batch), block 256. 128x128 tile, BK=32, 16x16x32 MFMA.
// mode 0: plain bf16 out.
// mode 1: bf16 out with per-head softmax over the wave's 64 n-cols (one head), *SCALE_.
// mode 2: fp32 out + bias[m], fused GroupNorm stats (atomicAdd sum/sumsq to stats[b*2]).
__global__ __launch_bounds__(256) void gemm_bt(
    const ushortT* __restrict__ A, const ushortT* __restrict__ Bt,
    void* __restrict__ Cc, const float* __restrict__ bias, float* __restrict__ stats,
    int K, int lda, int ldb, int ldc, int mode,
    unsigned long long bsA, unsigned long long bsB, unsigned long long bsC) {
  __shared__ ushortT As[128 * 32];
  __shared__ ushortT Bs[128 * 32];
  const int b = blockIdx.z;
  A += (size_t)b * bsA; Bt += (size_t)b * bsB;
  const int m0 = blockIdx.y * 128, n0 = blockIdx.x * 128;
  const int tid = threadIdx.x;
  const int w = tid >> 6;
  const int wm = (w >> 1) * 64, wn = (w & 1) * 64;
  const int l = tid & 63;
  const int quad = l >> 4, ln = l & 15;
  floatx4 acc[4][4];
#pragma unroll
  for (int i = 0; i < 4; i++)
#pragma unroll
    for (int j = 0; j < 4; j++) acc[i][j] = (floatx4){0.f, 0.f, 0.f, 0.f};

  for (int kb = 0; kb < K; kb += 32) {
#pragma unroll
    for (int i = 0; i < 2; ++i) {
      int wci = i * 256 + (tid & 192);   // wave-uniform chunk base
      int ci  = wci + (tid & 63);
      int row = ci >> 2, col = (ci & 3) << 3;
      GLD16(&A[(size_t)(m0 + row) * lda + kb + col], &As[wci * 8]);
      GLD16(&Bt[(size_t)(n0 + row) * ldb + kb + col], &Bs[wci * 8]);
    }
    __syncthreads();
    short8 af[4], bfv[4];
#pragma unroll
    for (int i = 0; i < 4; i++) af[i] = *(const short8*)(&As[(wm + i * 16 + ln) * 32 + quad * 8]);
#pragma unroll
    for (int j = 0; j < 4; j++) bfv[j] = *(const short8*)(&Bs[(wn + j * 16 + ln) * 32 + quad * 8]);
#pragma unroll
    for (int i = 0; i < 4; i++)
#pragma unroll
      for (int j = 0; j < 4; j++)
        acc[i][j] = __builtin_amdgcn_mfma_f32_16x16x32_bf16(af[i], bfv[j], acc[i][j], 0, 0, 0);
    __syncthreads();
  }

  if (mode == 0) {
    ushortT* Co = (ushortT*)Cc + (size_t)b * bsC;
#pragma unroll
    for (int i = 0; i < 4; i++)
#pragma unroll
      for (int r = 0; r < 4; r++) {
        int row = m0 + wm + i * 16 + quad * 4 + r;
#pragma unroll
        for (int j = 0; j < 4; j++)
          Co[(size_t)row * ldc + n0 + wn + j * 16 + ln] = f2bf(acc[i][j][r]);
      }
  } else if (mode == 1) {
    // per row: softmax over this wave's 64 n-cols (= one head's d dim), * SCALE_
    ushortT* Co = (ushortT*)Cc + (size_t)b * bsC;
#pragma unroll
    for (int i = 0; i < 4; i++)
#pragma unroll
      for (int r = 0; r < 4; r++) {
        int row = m0 + wm + i * 16 + quad * 4 + r;
        float v0 = acc[i][0][r], v1 = acc[i][1][r], v2 = acc[i][2][r], v3 = acc[i][3][r];
        float mx = fmaxf(fmaxf(v0, v1), fmaxf(v2, v3));
#pragma unroll
        for (int off = 1; off < 16; off <<= 1) mx = fmaxf(mx, __shfl_xor(mx, off));
        float e0 = expf(v0 - mx), e1 = expf(v1 - mx), e2 = expf(v2 - mx), e3 = expf(v3 - mx);
        float s = e0 + e1 + e2 + e3;
#pragma unroll
        for (int off = 1; off < 16; off <<= 1) s += __shfl_xor(s, off);
        float inv = SCALE_ / s;
        Co[(size_t)row * ldc + n0 + wn + 0 * 16 + ln] = f2bf(e0 * inv);
        Co[(size_t)row * ldc + n0 + wn + 1 * 16 + ln] = f2bf(e1 * inv);
        Co[(size_t)row * ldc + n0 + wn + 2 * 16 + ln] = f2bf(e2 * inv);
        Co[(size_t)row * ldc + n0 + wn + 3 * 16 + ln] = f2bf(e3 * inv);
      }
  } else {
    float* Co = (float*)Cc + (size_t)b * bsC;
    float s = 0.f, ss = 0.f;
#pragma unroll
    for (int i = 0; i < 4; i++)
#pragma unroll
      for (int r = 0; r < 4; r++) {
        int row = m0 + wm + i * 16 + quad * 4 + r;
        float bv = bias[row];
#pragma unroll
        for (int j = 0; j < 4; j++) {
          float val = acc[i][j][r] + bv;
          Co[(size_t)row * ldc + n0 + wn + j * 16 + ln] = val;
          s += val; ss += val * val;
        }
      }
#pragma unroll
    for (int off = 1; off < 64; off <<= 1) { s += __shfl_xor(s, off); ss += __shfl_xor(ss, off); }
    if (l == 0) {
      atomicAdd(&stats[b * 2], s);
      atomicAdd(&stats[b * 2 + 1], ss);
    }
  }
}

// ---------------- softmax over t (4096, contiguous) for k rows of kv ----------------
__global__ __launch_bounds__(256) void softmax_k(ushortT* kv) {
  int b = blockIdx.x >> 9, o = blockIdx.x & 511;
  ushortT* p = kv + ((size_t)b * 1024 + o) * T_;
  int tid = threadIdx.x, w = tid >> 6, l = tid & 63;
  float f[16];
  float mx = -1e30f;
#pragma unroll
  for (int c = 0; c < 2; ++c) {
    ushort8 v = *(const ushort8*)(p + (size_t)(c * 256 + tid) * 8);
#pragma unroll
    for (int j = 0; j < 8; j++) { f[c * 8 + j] = bf2f(v[j]); mx = fmaxf(mx, f[c * 8 + j]); }
  }
#pragma unroll
  for (int off = 1; off < 64; off <<= 1) mx = fmaxf(mx, __shfl_xor(mx, off));
  __shared__ float red[4], red2[4];
  if (l == 0) red[w] = mx;
  __syncthreads();
  mx = fmaxf(fmaxf(red[0], red[1]), fmaxf(red[2], red[3]));
  float s = 0.f;
#pragma unroll
  for (int i = 0; i < 16; i++) { f[i] = expf(f[i] - mx); s += f[i]; }
#pragma unroll
  for (int off = 1; off < 64; off <<= 1) s += __shfl_xor(s, off);
  if (l == 0) red2[w] = s;
  __syncthreads();
  s = red2[0] + red2[1] + red2[2] + red2[3];
  float inv = 1.f / s;
#pragma unroll
  for (int c = 0; c < 2; ++c) {
    ushort8 o;
#pragma unroll
    for (int j = 0; j < 8; j++) o[j] = f2bf(f[c * 8 + j] * inv);
    *(ushort8*)(p + (size_t)(c * 256 + tid) * 8) = o;
  }
}

// ---------------- context: ct2[b][h][d][e] += sum_t k_sm[d][t]*v[e][t] (split-K over t) ----------------
// grid (8 slices, 8 h, 16 b), block 64 (one wave). M=d(64), N=e(64), K=512 per slice.
__global__ __launch_bounds__(64) void context_kv(const ushortT* __restrict__ kv,
                                                 float* __restrict__ ct2) {
  __shared__ ushortT Vs[64 * 32];
  __shared__ ushortT Ks[64 * 32];
  const int slice = blockIdx.x, h = blockIdx.y, b = blockIdx.z;
  const int t0 = slice * 512;
  const ushortT* vrow = kv + ((size_t)b * 1024 + 512 + h * 64) * T_;
  const ushortT* krow = kv + ((size_t)b * 1024 + h * 64) * T_;
  const int tid = threadIdx.x, quad = tid >> 4, ln = tid & 15;
  floatx4 acc[4][4];
#pragma unroll
  for (int i = 0; i < 4; i++)
#pragma unroll
    for (int j = 0; j < 4; j++) acc[i][j] = (floatx4){0.f, 0.f, 0.f, 0.f};
  for (int kb = 0; kb < 512; kb += 32) {
#pragma unroll
    for (int i = 0; i < 4; ++i) {
      int ci = i * 64 + tid;
      int row = ci >> 2, col = (ci & 3) << 3;
      *(uint4*)(&Vs[row * 32 + col]) = *(const uint4*)(&vrow[(size_t)row * T_ + t0 + kb + col]);
      *(uint4*)(&Ks[row * 32 + col]) = *(const uint4*)(&krow[(size_t)row * T_ + t0 + kb + col]);
    }
    __syncthreads();
    short8 af[4], bfv[4];
#pragma unroll
    for (int i = 0; i < 4; i++) af[i] = *(const short8*)(&Ks[(i * 16 + ln) * 32 + quad * 8]);
#pragma unroll
    for (int j = 0; j < 4; j++) bfv[j] = *(const short8*)(&Vs[(j * 16 + ln) * 32 + quad * 8]);
#pragma unroll
    for (int i = 0; i < 4; i++)
#pragma unroll
      for (int j = 0; j < 4; j++)
        acc[i][j] = __builtin_amdgcn_mfma_f32_16x16x32_bf16(af[i], bfv[j], acc[i][j], 0, 0, 0);
    __syncthreads();
  }
  float* ctbh = ct2 + (size_t)(b * 8 + h) * 4096;
#pragma unroll
  for (int i = 0; i < 4; i++)
#pragma unroll
    for (int r = 0; r < 4; r++) {
      int d = i * 16 + quad * 4 + r;
#pragma unroll
      for (int j = 0; j < 4; j++) {
        int e = j * 16 + ln;
        atomicAdd(&ctbh[d * 64 + e], acc[i][j][r]);
      }
    }
}

// ---------------- fold: Wf[b][c][h*64+d] = sum_e Wout[c][h*64+e] * ct2[b][h][d][e] ----------------
// grid (8 c-tiles, 8 h, 16 b), block 64. M=c(64), N=d(64), K=e(64).
__global__ __launch_bounds__(64) void fold_ct(const ushortT* __restrict__ Wo,
                                              const float* __restrict__ ct2,
                                              ushortT* __restrict__ Wf) {
  __shared__ ushortT Cs[64 * 64];
  const int m0 = blockIdx.x * 64, h = blockIdx.y, b = blockIdx.z;
  const int tid = threadIdx.x, quad = tid >> 4, ln = tid & 15;
  const float* cb = ct2 + (size_t)(b * 8 + h) * 4096;
  // stage ct2 (fp32 [d][e]) -> bf16 LDS [d][e]
#pragma unroll
  for (int i = 0; i < 16; ++i) {
    int off = (i * 64 + tid) * 4;
    floatx4 v = *(const floatx4*)(cb + off);
    unsigned int p0 = (unsigned int)f2bf(v[0]) | ((unsigned int)f2bf(v[1]) << 16);
    unsigned int p1 = (unsigned int)f2bf(v[2]) | ((unsigned int)f2bf(v[3]) << 16);
    *(unsigned long long*)(&Cs[off]) = (unsigned long long)p0 | ((unsigned long long)p1 << 32);
  }
  __syncthreads();
  floatx4 acc[4][4];
#pragma unroll
  for (int i = 0; i < 4; i++)
#pragma unroll
    for (int j = 0; j < 4; j++) acc[i][j] = (floatx4){0.f, 0.f, 0.f, 0.f};
#pragma unroll
  for (int kk = 0; kk < 2; ++kk) {
    short8 af[4], bfv[4];
#pragma unroll
    for (int i = 0; i < 4; i++)
      af[i] = *(const short8*)(&Wo[(size_t)(m0 + i * 16 + ln) * 512 + h * 64 + kk * 32 + quad * 8]);
#pragma unroll
    for (int j = 0; j < 4; j++)
      bfv[j] = *(const short8*)(&Cs[(j * 16 + ln) * 64 + kk * 32 + quad * 8]);
#pragma unroll
    for (int i = 0; i < 4; i++)
#pragma unroll
      for (int j = 0; j < 4; j++)
        acc[i][j] = __builtin_amdgcn_mfma_f32_16x16x32_bf16(af[i], bfv[j], acc[i][j], 0, 0, 0);
  }
  ushortT* wfb = Wf + (size_t)b * 262144;
#pragma unroll
  for (int i = 0; i < 4; i++)
#pragma unroll
    for (int r = 0; r < 4; r++) {
      int c = m0 + i * 16 + quad * 4 + r;
#pragma unroll
      for (int j = 0; j < 4; j++)
        wfb[(size_t)c * 512 + h * 64 + j * 16 + ln] = f2bf(acc[i][j][r]);
    }
}

// ---------------- GroupNorm apply (in-place on fp32 d_out) ----------------
__global__ __launch_bounds__(256) void gn_apply(float* __restrict__ out,
                                                const float* __restrict__ stats,
                                                const float* __restrict__ gnw,
                                                const float* __restrict__ gnb) {
  int b = blockIdx.y;
  int i = blockIdx.x * 256 + threadIdx.x;  // 8-elem chunk index
  const float invN = 1.f / (float)(C_ * T_);
  float mean = stats[b * 2] * invN;
  float var = stats[b * 2 + 1] * invN - mean * mean;
  float inv = rsqrtf(var + EPS_);
  int c = i >> 9;
  float wv = gnw[c] * inv, bv = gnb[c];
  float* p = out + (size_t)b * C_ * T_ + (size_t)i * 8;
  floatx4 v0 = *(const floatx4*)p;
  floatx4 v1 = *(const floatx4*)(p + 4);
#pragma unroll
  for (int j = 0; j < 4; j++) v0[j] = (v0[j] - mean) * wv + bv;
#pragma unroll
  for (int j = 0; j < 4; j++) v1[j] = (v1[j] - mean) * wv + bv;
  *(floatx4*)p = v0;
  *(floatx4*)(p + 4) = v1;
}

extern "C" void kernel_launch(void* const* d_in, const int* in_sizes, int n_in,
                              void* d_out, int out_size, void* d_ws, size_t ws_size,
                              hipStream_t stream) {
  (void)in_sizes; (void)n_in; (void)out_size; (void)ws_size;
  const float* x    = (const float*)d_in[0];
  const float* Wqkv = (const float*)d_in[1];
  const float* Wout = (const float*)d_in[2];
  const float* bout = (const float*)d_in[3];
  const float* gnw  = (const float*)d_in[4];
  const float* gnb  = (const float*)d_in[5];
  float* out = (float*)d_out;

  // ws layout (<=132 MB, proven safe in R3/R4):
  //   xT    bf16 [b][t][512]      @ 0     (64 MB)  dead after the two QKV GEMMs
  //   Wf    bf16 [b][512][512]    @ 0     (8 MB)   overlays dead xT (created after)
  //   qT    bf16 [b][t][512]      @ 64M   (64 MB)  consumed directly by out GEMM
  //   Wq_bf bf16 [1536][512]      @ 128M  (1.5 MB)
  //   Wo_bf bf16 [512][512]       @ 129.5M(0.5 MB)
  //   ct2   fp32 [16][8][64][64]  @ 130M  (2 MB)   ctx[d][e] per (b,h)
  //   stats fp32 [32]             @ 132M
  // kv bf16 [b][1024][t] (128 MB) lives in d_out; dead before out GEMM writes.
  char* ws = (char*)d_ws;
  ushortT* xT   = (ushortT*)(ws);
  ushortT* Wf   = (ushortT*)(ws);
  ushortT* qT   = (ushortT*)(ws + 67108864);
  ushortT* Wqbf = (ushortT*)(ws + 134217728);
  ushortT* Wobf = (ushortT*)(ws + 135790592);
  float*   ct2  = (float*)(ws + 136314880);
  float* stats  = (float*)(ws + 138412032);
  ushortT* kv   = (ushortT*)d_out;

  cvt_f32_bf16<<<768, 256, 0, stream>>>(Wqkv, Wqbf, 196608);
  cvt_f32_bf16<<<256, 256, 0, stream>>>(Wout, Wobf, 65536);
  zero_f32<<<513, 256, 0, stream>>>(ct2, 131080);   // ct2 + stats

  transpose_x<<<dim3(64, 8, 16), 256, 0, stream>>>(x, xT);

  // kv[b][o'][t] = W_qkv[512+o'][:] . xT[b][t][:]   (M=1024, N=4096, K=512)
  gemm_bt<<<dim3(32, 8, 16), 256, 0, stream>>>(
      Wqbf + 512 * 512, xT, kv, nullptr, nullptr, 512, 512, 512, 4096, 0,
      0ULL, (unsigned long long)(T_ * 512), (unsigned long long)(1024 * T_));

  // qT[b][t][o] = softmax_d(xT . Wq) * SCALE        (M=4096, N=512, K=512, fused softmax)
  gemm_bt<<<dim3(4, 32, 16), 256, 0, stream>>>(
      xT, Wqbf, qT, nullptr, nullptr, 512, 512, 512, 512, 1,
      (unsigned long long)(T_ * 512), 0ULL, (unsigned long long)(T_ * 512));

  softmax_k<<<8192, 256, 0, stream>>>(kv);

  context_kv<<<dim3(8, 8, 16), 64, 0, stream>>>(kv, ct2);

  fold_ct<<<dim3(8, 8, 16), 64, 0, stream>>>(Wobf, ct2, Wf);

  // out[b][c][t] = Wf_b[c][:] . qT[b][t][:] + b_out[c], fused GN stats (fp32 out)
  gemm_bt<<<dim3(32, 4, 16), 256, 0, stream>>>(
      Wf, qT, out, bout, stats, 512, 512, 512, 4096, 2,
      262144ULL, (unsigned long long)(T_ * 512), (unsigned long long)(512 * T_));

  gn_apply<<<dim3(1024, 16), 256, 0, stream>>>(out, stats, gnw, gnb);
}